// Round 6
// baseline (459.863 us; speedup 1.0000x reference)
//
#include <hip/hip_runtime.h>
#include <hip/hip_bf16.h>

#define NIMG 256
#define CIN  256
#define PIX  784
#define DD   64
#define NP   200
#define NPP  208   // prototypes padded to 13*16
#define NCLS 10
// Diagnostic repetition: passes recompute identical results (bmin atomicMin is
// idempotent); >1 pass makes the kernel dispatch longer than the harness's
// ~120us fill dispatches so it appears in rocprof's top-5 with full counters.
#define NPASS 4

#define XS 264     // row stride (bf16) xlds/w1lds; 132 dw == 4 mod 32
#define HS 72      // row stride (bf16) htile/ftile/protolds; 36 dw == 4 mod 32

typedef __attribute__((ext_vector_type(8))) short bf16x8;
typedef __attribute__((ext_vector_type(4))) float f32x4;
typedef __attribute__((ext_vector_type(2))) unsigned int u32x2;

__device__ __forceinline__ unsigned short f2bf(float f) {
    union { float f; unsigned int u; } v; v.f = f;
    unsigned int r = v.u + 0x7fffu + ((v.u >> 16) & 1u);   // RNE
    return (unsigned short)(r >> 16);
}
__device__ __forceinline__ unsigned int pk2(float a, float b) {
    __hip_bfloat162 p = __float22bfloat162_rn(make_float2(a, b));
    return *(unsigned int*)&p;
}

#define MFMA(a, b, c) __builtin_amdgcn_mfma_f32_16x16x32_bf16((a), (b), (c), 0, 0, 0)

__global__ __launch_bounds__(1024, 4)
void proto_fused_kernel(const float* __restrict__ x,
                        const float* __restrict__ W1, const float* __restrict__ b1,
                        const float* __restrict__ W2, const float* __restrict__ b2,
                        const float* __restrict__ proto,
                        const float* __restrict__ lastW, const float* __restrict__ lastb,
                        float* __restrict__ out)
{
    __shared__ __align__(16) unsigned short xlds[2][64 * XS];   // 67.6 KB dbuf [px][c-swizzled]
    __shared__ __align__(16) unsigned short w1lds[64 * XS];     // 33.8 KB [o][c]
    __shared__ __align__(16) unsigned short htile[64 * HS];     //  9.2 KB [px][d]
    __shared__ __align__(16) unsigned short ftile[64 * HS];     //  9.2 KB [px][d]
    __shared__ __align__(16) unsigned short protolds[NPP * HS]; // 30.0 KB [p][d]
    __shared__ float p2lds[NPP];
    __shared__ float s2lds[4][64];      // per-quarter partial sums of f^2
    __shared__ float b1lds[DD], b2lds[DD];
    __shared__ unsigned int bmin[NPP];

    const int n    = blockIdx.x;
    const int t    = threadIdx.x;
    const int lane = t & 63;
    const int wave = t >> 6;      // 0..15
    const int q    = lane >> 4;
    const int l15  = lane & 15;
    const int s    = wave & 3;    // pixel strip (16 px) within 64-px tile
    const int dq   = wave >> 2;   // quarter: which 16-ch dt / which pt stride-4 set

    // ---------------- one-time staging ----------------
    #pragma unroll
    for (int i = 0; i < 16; ++i) {               // W1: 64x256
        int idx = t + i * 1024;
        w1lds[(idx >> 8) * XS + (idx & 255)] = f2bf(W1[idx]);
    }
    #pragma unroll
    for (int i = 0; i < 13; ++i) {               // protos: 200x64 = 12800
        int idx = t + i * 1024;
        if (idx < NP * DD)
            protolds[(idx >> 6) * HS + (idx & 63)] = f2bf(proto[idx]);
    }
    if (t < 512) {   // zero pad proto rows 200..207
        int p = NP + (t >> 6), d = t & 63;
        protolds[p * HS + d] = 0;
    }
    if (t < DD) { b1lds[t] = b1[t]; b2lds[t] = b2[t]; }
    if (t < NPP) {
        float acc = 0.f;
        if (t < NP) {
            const float4* pp = (const float4*)(proto + t * DD);
            #pragma unroll
            for (int i = 0; i < 16; ++i) {
                float4 v = pp[i];
                acc += v.x * v.x + v.y * v.y + v.z * v.z + v.w * v.w;
            }
        }
        p2lds[t] = acc;
        bmin[t] = 0x7f800000u;   // +inf bits (dist >= 0: uint order == float order)
    }

    // ---- W2 B-frags direct from global into registers (dt = dq) ----
    bf16x8 w2f[2];
    #pragma unroll
    for (int kk = 0; kk < 2; ++kk) {
        const float4* src = (const float4*)(W2 + (size_t)(dq * 16 + l15) * DD + kk * 32 + q * 8);
        float4 a = src[0], b = src[1];
        union { u32x2 u0; } ;
        union { unsigned int u[4]; bf16x8 h; } cv;
        cv.u[0] = pk2(a.x, a.y); cv.u[1] = pk2(a.z, a.w);
        cv.u[2] = pk2(b.x, b.y); cv.u[3] = pk2(b.z, b.w);
        w2f[kk] = cv.h;
    }

    // ---- x staging map: thread = 4 px x 4 ch; swizzled 8-ch blocks ----
    // store b64 banks: 16pg + 4((cblk^key)&7) + 2half covers all 32 banks
    // (4 lanes/bank) -> conflict-free; b128 reads unswizzle via key=(l15>>2)&3.
    const int px4 = ((t >> 2) & 15) * 4;
    const int cgi = (t & 3) | ((t >> 6) << 2);   // 0..63 ch-group of 4
    const int c4  = cgi * 4;
    const int key = (px4 >> 2) & 3;
    const int choff = ((((cgi >> 1) ^ key) << 3) | ((cgi & 1) << 2));  // shorts
    const float* xn = x + (size_t)n * CIN * PIX;

    float4 pf[4];
    auto load_tile = [&](int px0) {
        #pragma unroll
        for (int j = 0; j < 4; ++j) {
            const float* src = xn + (size_t)(c4 + j) * PIX + px0 + px4;
            float4 v;
            if (px0 + px4 + 3 < PIX) {
                v = *(const float4*)src;
            } else {
                v.x = (px0 + px4 + 0 < PIX) ? src[0] : 0.f;
                v.y = (px0 + px4 + 1 < PIX) ? src[1] : 0.f;
                v.z = (px0 + px4 + 2 < PIX) ? src[2] : 0.f;
                v.w = (px0 + px4 + 3 < PIX) ? src[3] : 0.f;
            }
            pf[j] = v;
        }
    };
    auto store_tile = [&](int buf) {   // register transpose -> 4x ds_write_b64
        #pragma unroll
        for (int r = 0; r < 4; ++r) {
            u32x2 uv;
            uv.x = pk2(((const float*)&pf[0])[r], ((const float*)&pf[1])[r]);
            uv.y = pk2(((const float*)&pf[2])[r], ((const float*)&pf[3])[r]);
            *(u32x2*)&xlds[buf][(px4 + r) * XS + choff] = uv;
        }
    };

    __syncthreads();   // staging visible

    // ---- per-wave resident fragments/constants ----
    bf16x8 w1f[8];
    #pragma unroll
    for (int kk = 0; kk < 8; ++kk)
        w1f[kk] = *(const bf16x8*)&w1lds[(dq * 16 + l15) * XS + kk * 32 + q * 8];
    const float b1r = b1lds[dq * 16 + l15];
    const float b2r = b2lds[dq * 16 + l15];
    float p2r[4];
    #pragma unroll
    for (int it = 0; it < 4; ++it) {
        int pt = dq + 4 * it;
        p2r[it] = p2lds[(pt < 13) ? (pt * 16 + l15) : 0];
    }
    float rmin[4];
    #pragma unroll
    for (int it = 0; it < 4; ++it) rmin[it] = 1e30f;

    const int rkey = l15 >> 2;   // unswizzle key for GEMM1 A-reads

    // ================= NPASS identical passes =================
    for (int pass = 0; pass < NPASS; ++pass) {
        // prologue: tile 0 -> xlds[0]; tile 1 in flight in pf
        load_tile(0);
        store_tile(0);
        load_tile(64);
        __syncthreads();

        for (int tl = 0; tl < 13; ++tl) {
            const int px0 = tl * 64;
            const int cur = tl & 1, nxt = cur ^ 1;

            // (a) stage next tile into the other buffer (no reader until 2 barriers later)
            if (tl < 12) store_tile(nxt);

            // (b) GEMM1: 16px strip s, 16 ch dt=dq, K=256
            {
                f32x4 acc = {0.f, 0.f, 0.f, 0.f};
                const int arow = (s * 16 + l15) * XS;
                #pragma unroll
                for (int kk = 0; kk < 8; ++kk) {
                    bf16x8 a = *(const bf16x8*)&xlds[cur][arow + (((kk * 4 + q) ^ rkey) << 3)];
                    acc = MFMA(a, w1f[kk], acc);
                }
                #pragma unroll
                for (int r = 0; r < 4; ++r)
                    htile[(s * 16 + q * 4 + r) * HS + dq * 16 + l15] =
                        f2bf(fmaxf(acc[r] + b1r, 0.f));
            }
            __syncthreads();   // (c)

            // (d) GEMM2 + sigmoid + s2 partials + f-write
            {
                bf16x8 ha0 = *(const bf16x8*)&htile[(s * 16 + l15) * HS + q * 8];
                bf16x8 ha1 = *(const bf16x8*)&htile[(s * 16 + l15) * HS + 32 + q * 8];
                f32x4 acc2 = {0.f, 0.f, 0.f, 0.f};
                acc2 = MFMA(ha0, w2f[0], acc2);
                acc2 = MFMA(ha1, w2f[1], acc2);
                #pragma unroll
                for (int r = 0; r < 4; ++r) {
                    const int prow = s * 16 + q * 4 + r;
                    float z = acc2[r] + b2r;
                    float fvr = __builtin_amdgcn_rcpf(1.0f + __builtin_amdgcn_exp2f(z * -1.44269504f));
                    ftile[prow * HS + dq * 16 + l15] = f2bf(fvr);
                    float v = fvr * fvr;
                    v += __shfl_xor(v, 1, 64);
                    v += __shfl_xor(v, 2, 64);
                    v += __shfl_xor(v, 4, 64);
                    v += __shfl_xor(v, 8, 64);
                    if (l15 == 0)
                        s2lds[dq][prow] = (px0 + prow < PIX) ? v : 1e30f;  // pad poison
                }
            }
            __syncthreads();   // (e)

            // (f) issue next prefetch FIRST (max vmcnt window: GEMM3+(a)+(b) before (c) drains)
            if (tl < 11) load_tile((tl + 2) * 64);

            // GEMM3: strip s vs 3-4 prototype tiles (pt = dq + 4*it) -> running min
            {
                bf16x8 fa0 = *(const bf16x8*)&ftile[(s * 16 + l15) * HS + q * 8];
                bf16x8 fa1 = *(const bf16x8*)&ftile[(s * 16 + l15) * HS + 32 + q * 8];
                float s2v[4];
                #pragma unroll
                for (int r = 0; r < 4; ++r) {
                    int pl = s * 16 + q * 4 + r;
                    s2v[r] = s2lds[0][pl] + s2lds[1][pl] + s2lds[2][pl] + s2lds[3][pl];
                }
                #pragma unroll
                for (int it = 0; it < 4; ++it) {
                    int pt = dq + 4 * it;
                    if (pt < 13) {
                        bf16x8 pb0 = *(const bf16x8*)&protolds[(pt * 16 + l15) * HS + q * 8];
                        bf16x8 pb1 = *(const bf16x8*)&protolds[(pt * 16 + l15) * HS + 32 + q * 8];
                        f32x4 a3 = {0.f, 0.f, 0.f, 0.f};
                        a3 = MFMA(fa0, pb0, a3);
                        a3 = MFMA(fa1, pb1, a3);
                        float m = 1e30f;
                        #pragma unroll
                        for (int r = 0; r < 4; ++r)
                            m = fminf(m, fmaxf(s2v[r] - 2.f * a3[r] + p2r[it], 0.f));
                        rmin[it] = fminf(rmin[it], m);
                    }
                }
            }
        }
        __syncthreads();   // pass end: protect next prologue's xlds[0] write
    }

    // ---- final reduction: regs -> bmin ----
    #pragma unroll
    for (int it = 0; it < 4; ++it) {
        int pt = dq + 4 * it;
        if (pt < 13) {
            float m = rmin[it];
            m = fminf(m, __shfl_xor(m, 16, 64));
            m = fminf(m, __shfl_xor(m, 32, 64));
            if (lane < 16) atomicMin(&bmin[pt * 16 + l15], __float_as_uint(m));
        }
    }
    __syncthreads();

    // ---------------- epilogue: min_distances + logits ----------------
    if (t < NP) {
        out[NIMG * NCLS + (size_t)n * NP + t] = __uint_as_float(bmin[t]);
    }
    if (t < 320) {
        int c = t >> 5, j = t & 31;
        float acc = 0.f;
        for (int p = j; p < NP; p += 32)
            acc += __uint_as_float(bmin[p]) * lastW[c * NP + p];
        acc += __shfl_xor(acc, 1, 32);
        acc += __shfl_xor(acc, 2, 32);
        acc += __shfl_xor(acc, 4, 32);
        acc += __shfl_xor(acc, 8, 32);
        acc += __shfl_xor(acc, 16, 32);
        if (j == 0) out[(size_t)n * NCLS + c] = -acc + lastb[c];
    }
}

extern "C" void kernel_launch(void* const* d_in, const int* in_sizes, int n_in,
                              void* d_out, int out_size, void* d_ws, size_t ws_size,
                              hipStream_t stream) {
    const float* x     = (const float*)d_in[0];
    const float* W1    = (const float*)d_in[1];
    const float* b1    = (const float*)d_in[2];
    const float* W2    = (const float*)d_in[3];
    const float* b2    = (const float*)d_in[4];
    const float* proto = (const float*)d_in[5];
    const float* lastW = (const float*)d_in[6];
    const float* lastb = (const float*)d_in[7];
    float* out = (float*)d_out;

    proto_fused_kernel<<<dim3(NIMG), dim3(1024), 0, stream>>>(
        x, W1, b1, W2, b2, proto, lastW, lastb, out);
}

// Round 7
// 322.939 us; speedup vs baseline: 1.4240x; 1.4240x over previous
//
#include <hip/hip_runtime.h>
#include <hip/hip_bf16.h>

#define NIMG 256
#define CIN  256
#define PIX  784
#define DD   64
#define NP   200
#define NCLS 10

#define XS 264     // row stride (bf16) xlds/w1lds; 132 dw == 4 mod 32
#define HS 72      // row stride (bf16) htile/ftile; 36 dw == 4 mod 32

typedef __attribute__((ext_vector_type(8))) short bf16x8;
typedef __attribute__((ext_vector_type(4))) float f32x4;
typedef __attribute__((ext_vector_type(2))) unsigned int u32x2;

__device__ __forceinline__ unsigned short f2bf(float f) {
    union { float f; unsigned int u; } v; v.f = f;
    unsigned int r = v.u + 0x7fffu + ((v.u >> 16) & 1u);   // RNE
    return (unsigned short)(r >> 16);
}
__device__ __forceinline__ unsigned int pk2(float a, float b) {
    __hip_bfloat162 p = __float22bfloat162_rn(make_float2(a, b));
    return *(unsigned int*)&p;
}

#define MFMA(a, b, c) __builtin_amdgcn_mfma_f32_16x16x32_bf16((a), (b), (c), 0, 0, 0)

__global__ __launch_bounds__(1024, 4)
void proto_fused_kernel(const float* __restrict__ x,
                        const float* __restrict__ W1, const float* __restrict__ b1,
                        const float* __restrict__ W2, const float* __restrict__ b2,
                        const float* __restrict__ proto,
                        const float* __restrict__ lastW, const float* __restrict__ lastb,
                        float* __restrict__ out)
{
    __shared__ __align__(16) unsigned short xlds[2][64 * XS];   // 67.6 KB dbuf [px][c-swizzled]
    __shared__ __align__(16) unsigned short w1lds[64 * XS];     // 33.8 KB [o][c] (init-only use)
    __shared__ __align__(16) unsigned short htile[64 * HS];     //  9.2 KB [px][d]
    __shared__ __align__(16) unsigned short ftile[64 * HS];     //  9.2 KB [px][d]
    __shared__ float p2lds[208];
    __shared__ float b1lds[DD], b2lds[DD];
    __shared__ unsigned int bmin[208];

    const int n    = blockIdx.x;
    const int t    = threadIdx.x;
    const int lane = t & 63;
    const int wave = t >> 6;      // 0..15
    const int q    = lane >> 4;
    const int l15  = lane & 15;
    const int s    = wave & 3;    // pixel strip (16 px) within 64-px tile
    const int dq   = wave >> 2;   // quarter: 16-ch slice of d / stride-4 proto-tile set

    // ---------------- one-time staging ----------------
    #pragma unroll
    for (int i = 0; i < 16; ++i) {               // W1: 64x256
        int idx = t + i * 1024;
        w1lds[(idx >> 8) * XS + (idx & 255)] = f2bf(W1[idx]);
    }
    if (t < DD) { b1lds[t] = b1[t]; b2lds[t] = b2[t]; }
    if (t < 208) {
        float acc = 0.f;
        if (t < NP) {
            const float4* pp = (const float4*)(proto + t * DD);
            #pragma unroll
            for (int i = 0; i < 16; ++i) {
                float4 v = pp[i];
                acc += v.x * v.x + v.y * v.y + v.z * v.z + v.w * v.w;
            }
        }
        p2lds[t] = acc;
        bmin[t] = 0x7f800000u;   // +inf bits (dist >= 0: uint order == float order)
    }

    // ---- W2 B-frags direct from global into registers (dt = dq) ----
    bf16x8 w2f[2];
    #pragma unroll
    for (int kk = 0; kk < 2; ++kk) {
        const float4* src = (const float4*)(W2 + (size_t)(dq * 16 + l15) * DD + kk * 32 + q * 8);
        float4 a = src[0], b = src[1];
        union { unsigned int u[4]; bf16x8 h; } cv;
        cv.u[0] = pk2(a.x, a.y); cv.u[1] = pk2(a.z, a.w);
        cv.u[2] = pk2(b.x, b.y); cv.u[3] = pk2(b.z, b.w);
        w2f[kk] = cv.h;
    }

    // ---- prototype B-frags direct from global into registers (pt = dq + 4*it) ----
    bf16x8 pb0[4], pb1[4];
    #pragma unroll
    for (int it = 0; it < 4; ++it) {
        int pt = dq + 4 * it;
        int p  = pt * 16 + l15;
        int pr = (pt < 13 && p < NP) ? p : (NP - 1);   // clamp; results discarded
        const float4* src = (const float4*)(proto + (size_t)pr * DD + q * 8);
        float4 a = src[0], b = src[1];                 // k = q*8 .. q*8+7
        float4 c = src[8], d = src[9];                 // k = 32 + q*8 ..
        union { unsigned int u[4]; bf16x8 h; } c0, c1;
        c0.u[0] = pk2(a.x, a.y); c0.u[1] = pk2(a.z, a.w);
        c0.u[2] = pk2(b.x, b.y); c0.u[3] = pk2(b.z, b.w);
        c1.u[0] = pk2(c.x, c.y); c1.u[1] = pk2(c.z, c.w);
        c1.u[2] = pk2(d.x, d.y); c1.u[3] = pk2(d.z, d.w);
        pb0[it] = c0.h; pb1[it] = c1.h;
    }

    // ---- x staging map: thread = 4 px x 4 ch; swizzled 8-ch blocks (R6-proven) ----
    const int px4 = ((t >> 2) & 15) * 4;
    const int cgi = (t & 3) | ((t >> 6) << 2);   // 0..63 ch-group of 4
    const int c4  = cgi * 4;
    const int key = (px4 >> 2) & 3;
    const int choff = ((((cgi >> 1) ^ key) << 3) | ((cgi & 1) << 2));  // shorts
    const float* xn = x + (size_t)n * CIN * PIX;

    float4 pf[4];
    auto load_tile = [&](int px0) {
        #pragma unroll
        for (int j = 0; j < 4; ++j) {
            const float* src = xn + (size_t)(c4 + j) * PIX + px0 + px4;
            float4 v;
            if (px0 + px4 + 3 < PIX) {
                v = *(const float4*)src;
            } else {
                v.x = (px0 + px4 + 0 < PIX) ? src[0] : 0.f;
                v.y = (px0 + px4 + 1 < PIX) ? src[1] : 0.f;
                v.z = (px0 + px4 + 2 < PIX) ? src[2] : 0.f;
                v.w = (px0 + px4 + 3 < PIX) ? src[3] : 0.f;
            }
            pf[j] = v;
        }
    };
    auto store_tile = [&](int buf) {   // register transpose -> 4x ds_write_b64
        #pragma unroll
        for (int r = 0; r < 4; ++r) {
            u32x2 uv;
            uv.x = pk2(((const float*)&pf[0])[r], ((const float*)&pf[1])[r]);
            uv.y = pk2(((const float*)&pf[2])[r], ((const float*)&pf[3])[r]);
            *(u32x2*)&xlds[buf][(px4 + r) * XS + choff] = uv;
        }
    };

    __syncthreads();   // staging visible

    // ---- per-wave resident fragments/constants ----
    bf16x8 w1f[8];
    #pragma unroll
    for (int kk = 0; kk < 8; ++kk)
        w1f[kk] = *(const bf16x8*)&w1lds[(dq * 16 + l15) * XS + kk * 32 + q * 8];
    const float b1r = b1lds[dq * 16 + l15];
    const float b2r = b2lds[dq * 16 + l15];
    float p2r[4];
    #pragma unroll
    for (int it = 0; it < 4; ++it) {
        int pt = dq + 4 * it;
        p2r[it] = p2lds[(pt < 13) ? (pt * 16 + l15) : 0];
    }
    float rmin[4];
    #pragma unroll
    for (int it = 0; it < 4; ++it) rmin[it] = 1e30f;

    const int rkey = l15 >> 2;   // unswizzle key for GEMM1 A-reads

    // prologue: tile 0 -> xlds[0]; tile 1 in flight in pf
    load_tile(0);
    store_tile(0);
    load_tile(64);
    __syncthreads();

    // ---------------- main loop: 13 tiles, 2 barriers each ----------------
    for (int tl = 0; tl < 13; ++tl) {
        const int cur = tl & 1, nxt = cur ^ 1;

        // (a) stage next tile into the other buffer
        if (tl < 12) store_tile(nxt);

        // (b) GEMM1: strip s, 16 ch dt=dq, K=256
        {
            f32x4 acc = {0.f, 0.f, 0.f, 0.f};
            const int arow = (s * 16 + l15) * XS;
            #pragma unroll
            for (int kk = 0; kk < 8; ++kk) {
                bf16x8 a = *(const bf16x8*)&xlds[cur][arow + (((kk * 4 + q) ^ rkey) << 3)];
                acc = MFMA(a, w1f[kk], acc);
            }
            #pragma unroll
            for (int r = 0; r < 4; ++r)
                htile[(s * 16 + q * 4 + r) * HS + dq * 16 + l15] =
                    f2bf(fmaxf(acc[r] + b1r, 0.f));
        }
        __syncthreads();   // (c)

        // (d) GEMM2 + sigmoid -> ftile (no s2 LDS path anymore)
        {
            bf16x8 ha0 = *(const bf16x8*)&htile[(s * 16 + l15) * HS + q * 8];
            bf16x8 ha1 = *(const bf16x8*)&htile[(s * 16 + l15) * HS + 32 + q * 8];
            f32x4 acc2 = {0.f, 0.f, 0.f, 0.f};
            acc2 = MFMA(ha0, w2f[0], acc2);
            acc2 = MFMA(ha1, w2f[1], acc2);
            #pragma unroll
            for (int r = 0; r < 4; ++r) {
                float z = acc2[r] + b2r;
                float fvr = __builtin_amdgcn_rcpf(1.0f + __builtin_amdgcn_exp2f(z * -1.44269504f));
                ftile[(s * 16 + q * 4 + r) * HS + dq * 16 + l15] = f2bf(fvr);
            }
        }
        __syncthreads();   // (e)

        // (f) prefetch tile tl+2 (max vmcnt window before next (a)'s use)
        if (tl < 11) load_tile((tl + 2) * 64);

        // (g) GEMM3: Gram-diagonal s2 + prototype distances -> running min
        {
            bf16x8 fa0 = *(const bf16x8*)&ftile[(s * 16 + l15) * HS + q * 8];
            bf16x8 fa1 = *(const bf16x8*)&ftile[(s * 16 + l15) * HS + 32 + q * 8];

            // s2 via Gram MFMA: A-frag == B-frag bit-identically, so
            // D = fa.fa^T is the pixel Gram matrix; diag D[i][i] = sum f^2,
            // held in lane 16*(i>>2)+i reg i&3 -> srcLane 20q+r, reg r.
            f32x4 g = {0.f, 0.f, 0.f, 0.f};
            g = MFMA(fa0, fa0, g);
            g = MFMA(fa1, fa1, g);
            float s2v[4];
            #pragma unroll
            for (int r = 0; r < 4; ++r)
                s2v[r] = __shfl(g[r], 20 * q + r, 64);

            // strips are fully valid or fully invalid (PIX = 49*16)
            if (tl * 64 + s * 16 < PIX) {
                #pragma unroll
                for (int it = 0; it < 4; ++it) {
                    int pt = dq + 4 * it;
                    if (pt < 13) {
                        f32x4 a3 = {0.f, 0.f, 0.f, 0.f};
                        a3 = MFMA(fa0, pb0[it], a3);
                        a3 = MFMA(fa1, pb1[it], a3);
                        float m = 1e30f;
                        #pragma unroll
                        for (int r = 0; r < 4; ++r)
                            m = fminf(m, fmaxf(s2v[r] - 2.f * a3[r] + p2r[it], 0.f));
                        rmin[it] = fminf(rmin[it], m);
                    }
                }
            }
        }
    }

    // ---- final reduction: regs -> bmin ----
    #pragma unroll
    for (int it = 0; it < 4; ++it) {
        int pt = dq + 4 * it;
        if (pt < 13) {
            float m = rmin[it];
            m = fminf(m, __shfl_xor(m, 16, 64));
            m = fminf(m, __shfl_xor(m, 32, 64));
            if (lane < 16) atomicMin(&bmin[pt * 16 + l15], __float_as_uint(m));
        }
    }
    __syncthreads();

    // ---------------- epilogue: min_distances + logits ----------------
    if (t < NP) {
        out[NIMG * NCLS + (size_t)n * NP + t] = __uint_as_float(bmin[t]);
    }
    if (t < 320) {
        int c = t >> 5, j = t & 31;
        float acc = 0.f;
        for (int p = j; p < NP; p += 32)
            acc += __uint_as_float(bmin[p]) * lastW[c * NP + p];
        acc += __shfl_xor(acc, 1, 32);
        acc += __shfl_xor(acc, 2, 32);
        acc += __shfl_xor(acc, 4, 32);
        acc += __shfl_xor(acc, 8, 32);
        acc += __shfl_xor(acc, 16, 32);
        if (j == 0) out[(size_t)n * NCLS + c] = -acc + lastb[c];
    }
}

extern "C" void kernel_launch(void* const* d_in, const int* in_sizes, int n_in,
                              void* d_out, int out_size, void* d_ws, size_t ws_size,
                              hipStream_t stream) {
    const float* x     = (const float*)d_in[0];
    const float* W1    = (const float*)d_in[1];
    const float* b1    = (const float*)d_in[2];
    const float* W2    = (const float*)d_in[3];
    const float* b2    = (const float*)d_in[4];
    const float* proto = (const float*)d_in[5];
    const float* lastW = (const float*)d_in[6];
    const float* lastb = (const float*)d_in[7];
    float* out = (float*)d_out;

    proto_fused_kernel<<<dim3(NIMG), dim3(1024), 0, stream>>>(
        x, W1, b1, W2, b2, proto, lastW, lastb, out);
}